// Round 2
// baseline (886.590 us; speedup 1.0000x reference)
//
#include <hip/hip_runtime.h>
#include <hip/hip_bf16.h>

typedef short short8 __attribute__((ext_vector_type(8)));
typedef float floatx4 __attribute__((ext_vector_type(4)));
typedef unsigned short u16;

#define TILE 128
#define BK 32
#define LDSS 40   // ushort stride per LDS row: 32 + 8 pad (80 B = 20 banks -> <=2-way, free)

// fp32 -> bf16 round-to-nearest-even, manual bit math (no bf16 class types)
__device__ __forceinline__ u16 cvt_bf(float x) {
  unsigned u = __float_as_uint(x);
  unsigned r = 0x7FFFu + ((u >> 16) & 1u);
  return (u16)((u + r) >> 16);
}

// Generic C = A_cat @ B_cat^T (+bias) GEMM, bf16 MFMA, fp32 in/out.
// A: up to 3 row-major segments, each K-width 1024 (concat along K).
// B: [N x K] row-major, 2 segments: B0 width KB0, then B1 width 1024.
// MODE 0: out[row*N+col] = acc + bias0[col] (+bias1[col])
// MODE 1: no D write; per-row atomicAdd of sum_col Walpha[col]*tanh(acc+atth) into scores.
template<int MODE>
__global__ __launch_bounds__(256, 2)
void gemm_bt(const float* __restrict__ A0, const float* __restrict__ A1,
             const float* __restrict__ A2,
             const float* __restrict__ B0, const float* __restrict__ B1, int KB0,
             const float* __restrict__ bias0, const float* __restrict__ bias1,
             float* __restrict__ out,
             const float* __restrict__ atth, const float* __restrict__ Walpha,
             float* __restrict__ scores,
             int N, int K)
{
  __shared__ u16 sA[TILE * LDSS];
  __shared__ u16 sB[TILE * LDSS];

  const int tid   = threadIdx.x;
  const int Mbase = blockIdx.y * TILE;
  const int Nbase = blockIdx.x * TILE;
  const int r0  = tid >> 3;        // 0..31 (staging row)
  const int c4  = (tid & 7) * 4;   // 0..28 (staging col, floats)
  const int lane = tid & 63;
  const int quad = lane >> 4;
  const int l15  = lane & 15;
  const int w    = tid >> 6;       // wave 0..3
  const int wvm  = w >> 1, wvn = w & 1;

  floatx4 acc[4][4] = {};

  const int nkt = K / BK;
  for (int kt = 0; kt < nkt; ++kt) {
    const int k0 = kt * BK;
    const float* Ap;
    { const int seg = k0 >> 10;
      Ap = (seg == 0) ? A0 : ((seg == 1) ? A1 : A2); }
    const int colA = k0 & 1023;
    const float* Bp; int rsB, colB;
    if (k0 < KB0) { Bp = B0; rsB = KB0;  colB = k0; }
    else          { Bp = B1; rsB = 1024; colB = k0 - KB0; }

    float4 av[4], bv[4];
#pragma unroll
    for (int i = 0; i < 4; ++i)
      av[i] = *reinterpret_cast<const float4*>(Ap + (size_t)(Mbase + r0 + 32 * i) * 1024 + colA + c4);
#pragma unroll
    for (int i = 0; i < 4; ++i)
      bv[i] = *reinterpret_cast<const float4*>(Bp + (size_t)(Nbase + r0 + 32 * i) * rsB + colB + c4);

    __syncthreads();   // prev tile fully consumed before overwrite
#pragma unroll
    for (int i = 0; i < 4; ++i) {
      ushort4 pa;
      pa.x = cvt_bf(av[i].x); pa.y = cvt_bf(av[i].y);
      pa.z = cvt_bf(av[i].z); pa.w = cvt_bf(av[i].w);
      *reinterpret_cast<ushort4*>(&sA[(r0 + 32 * i) * LDSS + c4]) = pa;
      ushort4 pb;
      pb.x = cvt_bf(bv[i].x); pb.y = cvt_bf(bv[i].y);
      pb.z = cvt_bf(bv[i].z); pb.w = cvt_bf(bv[i].w);
      *reinterpret_cast<ushort4*>(&sB[(r0 + 32 * i) * LDSS + c4]) = pb;
    }
    __syncthreads();

    short8 af[4], bf[4];
#pragma unroll
    for (int mt = 0; mt < 4; ++mt)
      af[mt] = *reinterpret_cast<const short8*>(&sA[(wvm * 64 + mt * 16 + l15) * LDSS + quad * 8]);
#pragma unroll
    for (int nt = 0; nt < 4; ++nt)
      bf[nt] = *reinterpret_cast<const short8*>(&sB[(wvn * 64 + nt * 16 + l15) * LDSS + quad * 8]);
#pragma unroll
    for (int mt = 0; mt < 4; ++mt)
#pragma unroll
      for (int nt = 0; nt < 4; ++nt)
        acc[mt][nt] = __builtin_amdgcn_mfma_f32_16x16x32_bf16(af[mt], bf[nt], acc[mt][nt], 0, 0, 0);
  }

  if (MODE == 0) {
#pragma unroll
    for (int nt = 0; nt < 4; ++nt) {
      const int col = Nbase + wvn * 64 + nt * 16 + l15;
      const float bcol = bias0[col] + (bias1 ? bias1[col] : 0.0f);
#pragma unroll
      for (int mt = 0; mt < 4; ++mt) {
        const int rowb = Mbase + wvm * 64 + mt * 16 + quad * 4;
#pragma unroll
        for (int r = 0; r < 4; ++r)
          out[(size_t)(rowb + r) * N + col] = acc[mt][nt][r] + bcol;
      }
    }
  } else {
    // all rows of this wave's 64-row stripe belong to one batch b (64 == S)
    const int b = (Mbase + wvm * 64) >> 6;
    float rs[4][4] = {};
#pragma unroll
    for (int nt = 0; nt < 4; ++nt) {
      const int col = Nbase + wvn * 64 + nt * 16 + l15;
      const float wa = Walpha[col];
      const float ah = atth[(size_t)b * 512 + col];
#pragma unroll
      for (int mt = 0; mt < 4; ++mt)
#pragma unroll
        for (int r = 0; r < 4; ++r)
          rs[mt][r] += wa * tanhf(acc[mt][nt][r] + ah);
    }
#pragma unroll
    for (int mt = 0; mt < 4; ++mt)
#pragma unroll
      for (int r = 0; r < 4; ++r) {
        float v = rs[mt][r];
        v += __shfl_xor(v, 1);
        v += __shfl_xor(v, 2);
        v += __shfl_xor(v, 4);
        v += __shfl_xor(v, 8);
        if (l15 == 0) {
          const int row = Mbase + wvm * 64 + mt * 16 + quad * 4 + r; // = b*64 + s
          atomicAdd(&scores[row], v);
        }
      }
  }
}

__global__ __launch_bounds__(256)
void init_scores(float* __restrict__ scores, const float* __restrict__ b_alpha)
{
  const int i = blockIdx.x * 256 + threadIdx.x;
  if (i < 65536) scores[i] = b_alpha[0];
}

// masked softmax over S=64 (exp*m / sum(exp*m); softmax denom cancels) + weighted clip sum
__global__ __launch_bounds__(256)
void softmax_ctx(const float* __restrict__ scores, const int* __restrict__ mask,
                 const float* __restrict__ clip, float* __restrict__ att)
{
  __shared__ float w[64];
  const int b = blockIdx.x;
  const int tid = threadIdx.x;
  if (tid < 64) {
    const float v = scores[b * 64 + tid];
    float mx = v;
#pragma unroll
    for (int d = 32; d; d >>= 1) mx = fmaxf(mx, __shfl_xor(mx, d));
    const float e = expf(v - mx) * (float)mask[b * 64 + tid];
    float s = e;
#pragma unroll
    for (int d = 32; d; d >>= 1) s += __shfl_xor(s, d);
    w[tid] = e / s;
  }
  __syncthreads();
  const int d4 = tid * 4;
  const float* cb = clip + (size_t)b * 64 * 1024 + d4;
  float4 acc = make_float4(0.f, 0.f, 0.f, 0.f);
#pragma unroll 8
  for (int s = 0; s < 64; ++s) {
    const float wt = w[s];
    const float4 c = *reinterpret_cast<const float4*>(cb + (size_t)s * 1024);
    acc.x += wt * c.x; acc.y += wt * c.y; acc.z += wt * c.z; acc.w += wt * c.w;
  }
  *reinterpret_cast<float4*>(att + (size_t)b * 1024 + d4) = acc;
}

__device__ __forceinline__ float sigm(float x) { return 1.0f / (1.0f + expf(-x)); }

// gates[b, 0:4096] = [i|f|g|o]; writes h to output slice + new_h, c to new_c
__global__ __launch_bounds__(256)
void lstm_ew(const float* __restrict__ gates, const float* __restrict__ cprev,
             float* __restrict__ out, int st)
{
  const int idx = blockIdx.x * 256 + threadIdx.x;  // 0..262143
  const int b = idx >> 8;
  const int r4 = (idx & 255) * 4;
  const float* g = gates + (size_t)b * 4096 + r4;
  const float4 gi = *reinterpret_cast<const float4*>(g);
  const float4 gf = *reinterpret_cast<const float4*>(g + 1024);
  const float4 gg = *reinterpret_cast<const float4*>(g + 2048);
  const float4 go = *reinterpret_cast<const float4*>(g + 3072);
  const float4 c  = *reinterpret_cast<const float4*>(cprev + (size_t)b * 1024 + r4);
  float4 cn, hn;
  cn.x = sigm(gf.x) * c.x + sigm(gi.x) * tanhf(gg.x);  hn.x = sigm(go.x) * tanhf(cn.x);
  cn.y = sigm(gf.y) * c.y + sigm(gi.y) * tanhf(gg.y);  hn.y = sigm(go.y) * tanhf(cn.y);
  cn.z = sigm(gf.z) * c.z + sigm(gi.z) * tanhf(gg.z);  hn.z = sigm(go.z) * tanhf(cn.z);
  cn.w = sigm(gf.w) * c.w + sigm(gi.w) * tanhf(gg.w);  hn.w = sigm(go.w) * tanhf(cn.w);
  *reinterpret_cast<float4*>(out + (size_t)b * 2048 + st * 1024 + r4) = hn;                      // output
  *reinterpret_cast<float4*>(out + 2097152 + (size_t)st * 1048576 + (size_t)b * 1024 + r4) = hn; // new_h
  *reinterpret_cast<float4*>(out + 4194304 + (size_t)st * 1048576 + (size_t)b * 1024 + r4) = cn; // new_c
}

extern "C" void kernel_launch(void* const* d_in, const int* in_sizes, int n_in,
                              void* d_out, int out_size, void* d_ws, size_t ws_size,
                              hipStream_t stream) {
  (void)in_sizes; (void)n_in; (void)out_size; (void)ws_size;
  const float* xt      = (const float*)d_in[0];
  const float* event   = (const float*)d_in[2];   // d_in[1] (video) is unused by the reference
  const float* clip    = (const float*)d_in[3];
  const int*   cmask   = (const int*)d_in[4];
  const float* state_h = (const float*)d_in[5];
  const float* state_c = (const float*)d_in[6];
  const float* W_ih0   = (const float*)d_in[7];
  const float* b_ih0   = (const float*)d_in[8];
  const float* W_hh0   = (const float*)d_in[9];
  const float* b_hh0   = (const float*)d_in[10];
  const float* W_ih1   = (const float*)d_in[11];
  const float* b_ih1   = (const float*)d_in[12];
  const float* W_hh1   = (const float*)d_in[13];
  const float* b_hh1   = (const float*)d_in[14];
  const float* W_ctx   = (const float*)d_in[15];
  const float* b_ctx   = (const float*)d_in[16];
  const float* W_h2a   = (const float*)d_in[17];
  const float* b_h2a   = (const float*)d_in[18];
  const float* W_alpha = (const float*)d_in[19];
  const float* b_alpha = (const float*)d_in[20];

  float* ws     = (float*)d_ws;
  float* gates  = ws;             // 1024*4096 f (reused by both streams)
  float* att_h  = ws + 4194304;   // 1024*512 f
  float* att    = ws + 4718592;   // 1024*1024 f
  float* scores = ws + 5767168;   // 1024*64 f   (total ~22.3 MB)

  const float* h0p = state_h;
  const float* h1p = state_h + 1048576;
  const float* c0p = state_c;
  const float* c1p = state_c + 1048576;
  float* out = (float*)d_out;

  // 1. scores <- b_alpha (atomic accumulation target)
  init_scores<<<256, 256, 0, stream>>>(scores, b_alpha);

  // 2. att_h = h1_prev @ W_h2a^T + b_h2a + b_ctx   [1024 x 512]
  gemm_bt<0><<<dim3(4, 8), 256, 0, stream>>>(h1p, h1p, h1p, W_h2a, nullptr, 1024,
                                             b_h2a, b_ctx, att_h,
                                             nullptr, nullptr, nullptr, 512, 1024);

  // 3. clip GEMM + fused tanh/W_alpha score reduction  [65536 x 512, K=1024]
  gemm_bt<1><<<dim3(4, 512), 256, 0, stream>>>(clip, clip, clip, W_ctx, nullptr, 1024,
                                               nullptr, nullptr, nullptr,
                                               att_h, W_alpha, scores, 512, 1024);

  // 4. masked softmax + weighted clip sum -> att [1024 x 1024]
  softmax_ctx<<<1024, 256, 0, stream>>>(scores, cmask, clip, att);

  // 5. gates0 = [xt|event|h0p] @ [W_ih0|W_hh0]^T + b_ih0 + b_hh0
  gemm_bt<0><<<dim3(32, 8), 256, 0, stream>>>(xt, event, h0p, W_ih0, W_hh0, 2048,
                                              b_ih0, b_hh0, gates,
                                              nullptr, nullptr, nullptr, 4096, 3072);
  // 6. LSTM stream 0 elementwise
  lstm_ew<<<1024, 256, 0, stream>>>(gates, c0p, out, 0);

  // 7. gates1 = [xt|att|h1p] @ [W_ih1|W_hh1]^T + b_ih1 + b_hh1  (reuses gates buffer)
  gemm_bt<0><<<dim3(32, 8), 256, 0, stream>>>(xt, att, h1p, W_ih1, W_hh1, 2048,
                                              b_ih1, b_hh1, gates,
                                              nullptr, nullptr, nullptr, 4096, 3072);
  // 8. LSTM stream 1 elementwise
  lstm_ew<<<1024, 256, 0, stream>>>(gates, c1p, out, 1);
}

// Round 3
// 813.200 us; speedup vs baseline: 1.0902x; 1.0902x over previous
//
#include <hip/hip_runtime.h>

typedef short short8 __attribute__((ext_vector_type(8)));
typedef float floatx4 __attribute__((ext_vector_type(4)));
typedef unsigned short u16;

// fp32 -> bf16 round-to-nearest-even (bit math; no bf16 class types)
__device__ __forceinline__ u16 cvt_bf(float x) {
  unsigned u = __float_as_uint(x);
  unsigned r = 0x7FFFu + ((u >> 16) & 1u);
  return (u16)((u + r) >> 16);
}

// async global->LDS, 16B per lane; LDS dest = base + lane*16 (wave-uniform base)
__device__ __forceinline__ void gll16(const u16* g, u16* l) {
  __builtin_amdgcn_global_load_lds(
      (__attribute__((address_space(1))) void*)(void*)const_cast<u16*>(g),
      (__attribute__((address_space(3))) void*)(void*)l, 16, 0, 0);
}

// ---------------------------------------------------------------------------
// Segmented fp32 -> bf16 conversion (weights + activations), 2048 elems/block.
// dst index = (e >> lw)*dstride + (e & (2^lw - 1)); dst base has col offset.
#define NSEG 11
struct ConvArgs {
  const float* src[NSEG];
  u16* dst[NSEG];
  unsigned lw[NSEG];
  unsigned dstride[NSEG];
  unsigned blk0[NSEG + 1];
};
__global__ __launch_bounds__(256)
void convert_seg(ConvArgs a) {
  const unsigned blk = blockIdx.x;
  int s = 0;
#pragma unroll
  for (int i = 1; i < NSEG; ++i) if (blk >= a.blk0[i]) s = i;
  const unsigned e0 = (blk - a.blk0[s]) * 2048u + threadIdx.x * 8u;
  const float* src = a.src[s] + e0;
  const float4 v0 = *(const float4*)src;
  const float4 v1 = *(const float4*)(src + 4);
  const unsigned row = e0 >> a.lw[s];
  const unsigned col = e0 & ((1u << a.lw[s]) - 1u);
  u16* d = a.dst[s] + (size_t)row * a.dstride[s] + col;
  short8 p;
  p[0] = (short)cvt_bf(v0.x); p[1] = (short)cvt_bf(v0.y);
  p[2] = (short)cvt_bf(v0.z); p[3] = (short)cvt_bf(v0.w);
  p[4] = (short)cvt_bf(v1.x); p[5] = (short)cvt_bf(v1.y);
  p[6] = (short)cvt_bf(v1.z); p[7] = (short)cvt_bf(v1.w);
  *(short8*)d = p;
}

// ---------------------------------------------------------------------------
// Kernel G: out[M,N] = A_bf16[M,K](stride sa) @ B_bf16[N,K]^T(stride sb) + biases
// Tile 64(M) x 128(N), BK=64, 256 thr / 4 waves, wave = 32x64 (2x4 MFMA tiles).
// Staging: global_load_lds 16B, xor-swizzled col-slots (rows are 128B -> same
// bank otherwise). LDS slot j of row r holds global col-block j ^ (r & 7).
__global__ __launch_bounds__(256, 2)
void gemm_g(const u16* __restrict__ A, int sa,
            const u16* __restrict__ B, int sb,
            const float* __restrict__ bias0, const float* __restrict__ bias1,
            float* __restrict__ out, int N, int K)
{
  __shared__ u16 sA[64 * 64];    // 8 KB, rows 128 B
  __shared__ u16 sB[128 * 64];   // 16 KB

  const int tid = threadIdx.x;
  const int lane = tid & 63, w = tid >> 6;
  const int quad = lane >> 4, l15 = lane & 15;
  const int wm = w >> 1, wn = w & 1;
  const int Mbase = blockIdx.y * 64, Nbase = blockIdx.x * 128;

  const int srow = lane >> 3;                 // row within 8-row chunk
  const int sslot = (lane & 7) ^ (srow & 7);  // fetch-side xor swizzle

  floatx4 acc[2][4] = {};

  for (int k0 = 0; k0 < K; k0 += 64) {
    __syncthreads();   // previous tile fully consumed
    // 24 chunks of 1 KB: 0..7 = A (8 rows each), 8..23 = B
#pragma unroll
    for (int j = 0; j < 6; ++j) {
      const int c = w + 4 * j;
      if (c < 8) {
        const int row = c * 8 + srow;
        gll16(A + (size_t)(Mbase + row) * sa + k0 + sslot * 8, &sA[c * 512]);
      } else {
        const int cb = c - 8;
        const int row = cb * 8 + srow;
        gll16(B + (size_t)(Nbase + row) * sb + k0 + sslot * 8, &sB[cb * 512]);
      }
    }
    __syncthreads();   // drains vmcnt (global_load_lds) at barrier

    short8 af[2][2], bf[4][2];
#pragma unroll
    for (int ks = 0; ks < 2; ++ks) {
#pragma unroll
      for (int mt = 0; mt < 2; ++mt) {
        const int row = wm * 32 + mt * 16 + l15;
        const int slot = (ks * 4 + quad) ^ (row & 7);
        af[mt][ks] = *(const short8*)&sA[row * 64 + slot * 8];
      }
#pragma unroll
      for (int nt = 0; nt < 4; ++nt) {
        const int row = wn * 64 + nt * 16 + l15;
        const int slot = (ks * 4 + quad) ^ (row & 7);
        bf[nt][ks] = *(const short8*)&sB[row * 64 + slot * 8];
      }
    }
#pragma unroll
    for (int ks = 0; ks < 2; ++ks)
#pragma unroll
      for (int mt = 0; mt < 2; ++mt)
#pragma unroll
        for (int nt = 0; nt < 4; ++nt)
          acc[mt][nt] = __builtin_amdgcn_mfma_f32_16x16x32_bf16(af[mt][ks], bf[nt][ks], acc[mt][nt], 0, 0, 0);
  }

#pragma unroll
  for (int nt = 0; nt < 4; ++nt) {
    const int col = Nbase + wn * 64 + nt * 16 + l15;
    const float bc = (bias0 ? bias0[col] : 0.f) + (bias1 ? bias1[col] : 0.f);
#pragma unroll
    for (int mt = 0; mt < 2; ++mt) {
      const int rb = Mbase + wm * 32 + mt * 16 + quad * 4;
#pragma unroll
      for (int r = 0; r < 4; ++r)
        out[(size_t)(rb + r) * N + col] = acc[mt][nt][r] + bc;
    }
  }
}

// ---------------------------------------------------------------------------
// Kernel C: per batch b, scores[s] = sum_h Walpha[h]*tanh((clip[b] @ Wc^T)[s,h]
// + atth[b,h]) then masked softmax -> wout[b][64]. One block per batch:
// 8 waves, wave tile 64(M) x 64(N), BK=32; clip read ONCE from HBM.
__global__ __launch_bounds__(512)
void clip_scores(const float* __restrict__ clip,   // [1024][64][1024] fp32
                 const u16* __restrict__ Wc,       // [512][1024] bf16
                 const float* __restrict__ atth,   // [1024][512] (incl. b_h2a+b_ctx)
                 const float* __restrict__ Walpha, // [512]
                 const int* __restrict__ mask,     // [1024][64]
                 float* __restrict__ wout)         // [1024][64]
{
  __shared__ u16 sA[64 * 40];     // padded stride 40 shorts (80 B), ds_write path
  __shared__ u16 sB[512 * 32];    // 32 KB, rows 64 B, xor-swizzled (global_load_lds)
  __shared__ float wsum[8][64];

  const int b = blockIdx.x;
  const int tid = threadIdx.x;
  const int lane = tid & 63, w = tid >> 6;   // 8 waves; wave w -> cols w*64..+63
  const int quad = lane >> 4, l15 = lane & 15;
  const float* Ab = clip + (size_t)b * 65536;

  floatx4 acc[4][4] = {};

  for (int k0 = 0; k0 < 1024; k0 += 32) {
    __syncthreads();
    {  // B: 32 chunks (16 rows x 64 B), wave w takes chunks w + 8j
      const int srow = lane >> 2;
      const int sslot = (lane & 3) ^ (srow & 3);
#pragma unroll
      for (int j = 0; j < 4; ++j) {
        const int c = w + 8 * j;
        const int row = c * 16 + srow;
        gll16(Wc + (size_t)row * 1024 + k0 + sslot * 8, &sB[c * 512]);
      }
    }
    if (w < 4) {  // A: 4 chunks, fp32 load + convert + ds_write (padded, no swizzle)
      const int srow = lane >> 2;
      const int scol = (lane & 3) * 8;
      const int row = w * 16 + srow;
      const float* src = Ab + (size_t)row * 1024 + k0 + scol;
      const float4 v0 = *(const float4*)src;
      const float4 v1 = *(const float4*)(src + 4);
      short8 p;
      p[0] = (short)cvt_bf(v0.x); p[1] = (short)cvt_bf(v0.y);
      p[2] = (short)cvt_bf(v0.z); p[3] = (short)cvt_bf(v0.w);
      p[4] = (short)cvt_bf(v1.x); p[5] = (short)cvt_bf(v1.y);
      p[6] = (short)cvt_bf(v1.z); p[7] = (short)cvt_bf(v1.w);
      *(short8*)&sA[row * 40 + scol] = p;
    }
    __syncthreads();

    short8 af[4], bfr[4];
#pragma unroll
    for (int mt = 0; mt < 4; ++mt)
      af[mt] = *(const short8*)&sA[(mt * 16 + l15) * 40 + quad * 8];
#pragma unroll
    for (int nt = 0; nt < 4; ++nt) {
      const int row = w * 64 + nt * 16 + l15;
      const int slot = quad ^ (row & 3);
      bfr[nt] = *(const short8*)&sB[row * 32 + slot * 8];
    }
#pragma unroll
    for (int mt = 0; mt < 4; ++mt)
#pragma unroll
      for (int nt = 0; nt < 4; ++nt)
        acc[mt][nt] = __builtin_amdgcn_mfma_f32_16x16x32_bf16(af[mt], bfr[nt], acc[mt][nt], 0, 0, 0);
  }

  // fused score epilogue: rs = sum over this wave's 64 cols of wa*tanh(acc+ah)
  float rs[4][4] = {};
#pragma unroll
  for (int nt = 0; nt < 4; ++nt) {
    const int col = w * 64 + nt * 16 + l15;
    const float wa = Walpha[col];
    const float ah = atth[(size_t)b * 512 + col];
#pragma unroll
    for (int mt = 0; mt < 4; ++mt)
#pragma unroll
      for (int r = 0; r < 4; ++r)
        rs[mt][r] += wa * tanhf(acc[mt][nt][r] + ah);
  }
#pragma unroll
  for (int mt = 0; mt < 4; ++mt)
#pragma unroll
    for (int r = 0; r < 4; ++r) {
      float v = rs[mt][r];
      v += __shfl_xor(v, 1); v += __shfl_xor(v, 2);
      v += __shfl_xor(v, 4); v += __shfl_xor(v, 8);
      if (l15 == 0) wsum[w][mt * 16 + quad * 4 + r] = v;
    }
  __syncthreads();
  if (tid < 64) {  // wave 0: cross-wave reduce + masked softmax (b_alpha cancels)
    float s = 0.f;
#pragma unroll
    for (int i = 0; i < 8; ++i) s += wsum[i][tid];
    float mx = s;
#pragma unroll
    for (int d = 32; d; d >>= 1) mx = fmaxf(mx, __shfl_xor(mx, d));
    const float e = expf(s - mx) * (float)mask[b * 64 + tid];
    float den = e;
#pragma unroll
    for (int d = 32; d; d >>= 1) den += __shfl_xor(den, d);
    wout[b * 64 + tid] = e / den;
  }
}

// ---------------------------------------------------------------------------
// ctx: att[b,:] = sum_s w[s]*clip[b,s,:]; writes bf16 directly into A1 rows
// (col offset 1024, stride 3072) so gates1 GEMM consumes it in place.
__global__ __launch_bounds__(256)
void ctx_att(const float* __restrict__ clip, const float* __restrict__ wbuf,
             u16* __restrict__ A1)
{
  __shared__ float w[64];
  const int b = blockIdx.x, tid = threadIdx.x;
  if (tid < 64) w[tid] = wbuf[b * 64 + tid];
  __syncthreads();
  const int d4 = tid * 4;
  const float* cb = clip + (size_t)b * 65536 + d4;
  float4 a = make_float4(0.f, 0.f, 0.f, 0.f);
#pragma unroll 8
  for (int s = 0; s < 64; ++s) {
    const float wt = w[s];
    const float4 c = *(const float4*)(cb + (size_t)s * 1024);
    a.x += wt * c.x; a.y += wt * c.y; a.z += wt * c.z; a.w += wt * c.w;
  }
  ushort4 p;
  p.x = cvt_bf(a.x); p.y = cvt_bf(a.y); p.z = cvt_bf(a.z); p.w = cvt_bf(a.w);
  *(ushort4*)&A1[(size_t)b * 3072 + 1024 + d4] = p;
}

// ---------------------------------------------------------------------------
__device__ __forceinline__ float sigm(float x) { return 1.0f / (1.0f + expf(-x)); }

__global__ __launch_bounds__(256)
void lstm_ew(const float* __restrict__ gates, const float* __restrict__ cprev,
             float* __restrict__ out, int st)
{
  const int idx = blockIdx.x * 256 + threadIdx.x;
  const int b = idx >> 8;
  const int r4 = (idx & 255) * 4;
  const float* g = gates + (size_t)b * 4096 + r4;
  const float4 gi = *(const float4*)g;
  const float4 gf = *(const float4*)(g + 1024);
  const float4 gg = *(const float4*)(g + 2048);
  const float4 go = *(const float4*)(g + 3072);
  const float4 c  = *(const float4*)(cprev + (size_t)b * 1024 + r4);
  float4 cn, hn;
  cn.x = sigm(gf.x) * c.x + sigm(gi.x) * tanhf(gg.x);  hn.x = sigm(go.x) * tanhf(cn.x);
  cn.y = sigm(gf.y) * c.y + sigm(gi.y) * tanhf(gg.y);  hn.y = sigm(go.y) * tanhf(cn.y);
  cn.z = sigm(gf.z) * c.z + sigm(gi.z) * tanhf(gg.z);  hn.z = sigm(go.z) * tanhf(cn.z);
  cn.w = sigm(gf.w) * c.w + sigm(gi.w) * tanhf(gg.w);  hn.w = sigm(go.w) * tanhf(cn.w);
  *(float4*)(out + (size_t)b * 2048 + st * 1024 + r4) = hn;
  *(float4*)(out + 2097152 + (size_t)st * 1048576 + (size_t)b * 1024 + r4) = hn;
  *(float4*)(out + 4194304 + (size_t)st * 1048576 + (size_t)b * 1024 + r4) = cn;
}

// ---------------------------------------------------------------------------
extern "C" void kernel_launch(void* const* d_in, const int* in_sizes, int n_in,
                              void* d_out, int out_size, void* d_ws, size_t ws_size,
                              hipStream_t stream) {
  (void)in_sizes; (void)n_in; (void)out_size; (void)ws_size;
  const float* xt      = (const float*)d_in[0];
  const float* event   = (const float*)d_in[2];   // d_in[1] (video) unused
  const float* clip    = (const float*)d_in[3];
  const int*   cmask   = (const int*)d_in[4];
  const float* state_h = (const float*)d_in[5];
  const float* state_c = (const float*)d_in[6];
  const float* W_ih0   = (const float*)d_in[7];
  const float* b_ih0   = (const float*)d_in[8];
  const float* W_hh0   = (const float*)d_in[9];
  const float* b_hh0   = (const float*)d_in[10];
  const float* W_ih1   = (const float*)d_in[11];
  const float* b_ih1   = (const float*)d_in[12];
  const float* W_hh1   = (const float*)d_in[13];
  const float* b_hh1   = (const float*)d_in[14];
  const float* W_ctx   = (const float*)d_in[15];
  const float* b_ctx   = (const float*)d_in[16];
  const float* W_h2a   = (const float*)d_in[17];
  const float* b_h2a   = (const float*)d_in[18];
  const float* W_alpha = (const float*)d_in[19];

  char* w8 = (char*)d_ws;                         // ~84 MB total
  float* gates = (float*)(w8 + 0);                // 1024x4096 fp32
  float* att_h = (float*)(w8 + 16777216);         // 1024x512  fp32
  float* wbuf  = (float*)(w8 + 18874368);         // 1024x64   fp32
  u16* A0 = (u16*)(w8 + 19136512);                // 1024x3072 bf16 [xt|event|h0p]
  u16* A1 = (u16*)(w8 + 25427968);                // 1024x3072 bf16 [xt|att|h1p]
  u16* W0 = (u16*)(w8 + 31719424);                // 4096x3072 bf16 [W_ih0|W_hh0]
  u16* W1 = (u16*)(w8 + 56885248);                // 4096x3072 bf16 [W_ih1|W_hh1]
  u16* Wc = (u16*)(w8 + 82051072);                // 512x1024  bf16
  u16* Wh = (u16*)(w8 + 83099648);                // 512x1024  bf16

  const float* h0p = state_h;
  const float* h1p = state_h + 1048576;
  const float* c0p = state_c;
  const float* c1p = state_c + 1048576;
  float* out = (float*)d_out;

  // 1. convert weights + activations to bf16 (single segmented pass)
  ConvArgs ca;
  const float* srcs[NSEG] = {W_ctx, W_h2a, W_ih0, W_hh0, W_ih1, W_hh1,
                             xt, event, h0p, xt, h1p};
  u16* dsts[NSEG] = {Wc, Wh, W0, W0 + 2048, W1, W1 + 2048,
                     A0, A0 + 1024, A0 + 2048, A1, A1 + 2048};
  const unsigned lws[NSEG]  = {10, 10, 11, 10, 11, 10, 10, 10, 10, 10, 10};
  const unsigned dstr[NSEG] = {1024, 1024, 3072, 3072, 3072, 3072,
                               3072, 3072, 3072, 3072, 3072};
  const unsigned nblk[NSEG] = {256, 256, 4096, 2048, 4096, 2048,
                               512, 512, 512, 512, 512};
  unsigned acc_b = 0;
  for (int i = 0; i < NSEG; ++i) {
    ca.src[i] = srcs[i]; ca.dst[i] = dsts[i];
    ca.lw[i] = lws[i]; ca.dstride[i] = dstr[i];
    ca.blk0[i] = acc_b; acc_b += nblk[i];
  }
  ca.blk0[NSEG] = acc_b;
  convert_seg<<<acc_b, 256, 0, stream>>>(ca);     // 15360 blocks

  // 2. att_h = h1p @ W_h2a^T + b_h2a + b_ctx   [1024 x 512]
  gemm_g<<<dim3(4, 16), 256, 0, stream>>>(A1 + 2048, 3072, Wh, 1024,
                                          b_h2a, b_ctx, att_h, 512, 1024);

  // 3. clip scores + masked softmax -> wbuf (clip read once; b_alpha cancels)
  clip_scores<<<1024, 512, 0, stream>>>(clip, Wc, att_h, W_alpha, cmask, wbuf);

  // 4. att = w @ clip  ->  bf16 into A1 middle columns
  ctx_att<<<1024, 256, 0, stream>>>(clip, wbuf, A1);

  // 5. gates0 = [xt|event|h0p] @ [W_ih0|W_hh0]^T + biases
  gemm_g<<<dim3(32, 16), 256, 0, stream>>>(A0, 3072, W0, 3072,
                                           b_ih0, b_hh0, gates, 4096, 3072);
  // 6. LSTM stream 0
  lstm_ew<<<1024, 256, 0, stream>>>(gates, c0p, out, 0);

  // 7. gates1 = [xt|att|h1p] @ [W_ih1|W_hh1]^T + biases
  gemm_g<<<dim3(32, 16), 256, 0, stream>>>(A1, 3072, W1, 3072,
                                           b_ih1, b_hh1, gates, 4096, 3072);
  // 8. LSTM stream 1
  lstm_ew<<<1024, 256, 0, stream>>>(gates, c1p, out, 1);
}

// Round 4
// 708.350 us; speedup vs baseline: 1.2516x; 1.1480x over previous
//
#include <hip/hip_runtime.h>

typedef short short8 __attribute__((ext_vector_type(8)));
typedef float floatx4 __attribute__((ext_vector_type(4)));
typedef unsigned short u16;

// fp32 -> bf16 round-to-nearest-even (bit math)
__device__ __forceinline__ u16 cvt_bf(float x) {
  unsigned u = __float_as_uint(x);
  unsigned r = 0x7FFFu + ((u >> 16) & 1u);
  return (u16)((u + r) >> 16);
}
__device__ __forceinline__ float bf2f(u16 h) {
  return __uint_as_float(((unsigned)h) << 16);
}
// async global->LDS, 16B/lane; LDS dest = uniform base + lane*16
__device__ __forceinline__ void gll16(const u16* g, u16* l) {
  __builtin_amdgcn_global_load_lds(
      (__attribute__((address_space(1))) void*)(void*)const_cast<u16*>(g),
      (__attribute__((address_space(3))) void*)(void*)l, 16, 0, 0);
}
// fast tanh/sigmoid via v_exp (args bounded ~|6| here; |x| form is overflow-safe)
__device__ __forceinline__ float fast_tanh(float x) {
  float t = __expf(-2.f * fabsf(x));
  float r = 1.f - 2.f * t / (1.f + t);
  return copysignf(r, x);
}
__device__ __forceinline__ float fast_sigm(float x) {
  return 1.f / (1.f + __expf(-x));
}

// ---------------------------------------------------------------------------
// Segmented fp32 -> bf16 convert, 2048 elems/block.
#define MAXSEG 9
struct ConvArgs {
  const float* src[MAXSEG];
  u16* dst[MAXSEG];
  unsigned lw[MAXSEG];       // row = e >> lw, col = e & ((1<<lw)-1)
  unsigned dstride[MAXSEG];
  unsigned blk0[MAXSEG + 1];
  int nseg;
};
__global__ __launch_bounds__(256)
void convert_seg(ConvArgs a) {
  const unsigned blk = blockIdx.x;
  int s = 0;
  for (int i = 1; i < a.nseg; ++i) if (blk >= a.blk0[i]) s = i;
  const unsigned e0 = (blk - a.blk0[s]) * 2048u + threadIdx.x * 8u;
  const float* src = a.src[s] + e0;
  const float4 v0 = *(const float4*)src;
  const float4 v1 = *(const float4*)(src + 4);
  const unsigned row = e0 >> a.lw[s];
  const unsigned col = e0 & ((1u << a.lw[s]) - 1u);
  u16* d = a.dst[s] + (size_t)row * a.dstride[s] + col;
  short8 p;
  p[0] = (short)cvt_bf(v0.x); p[1] = (short)cvt_bf(v0.y);
  p[2] = (short)cvt_bf(v0.z); p[3] = (short)cvt_bf(v0.w);
  p[4] = (short)cvt_bf(v1.x); p[5] = (short)cvt_bf(v1.y);
  p[6] = (short)cvt_bf(v1.z); p[7] = (short)cvt_bf(v1.w);
  *(short8*)d = p;
}
// flat fp32 -> bf16 (clip chunks)
__global__ __launch_bounds__(256)
void conv_flat(const float* __restrict__ src, u16* __restrict__ dst) {
  const size_t e = (size_t)blockIdx.x * 2048 + threadIdx.x * 8;
  const float4 v0 = *(const float4*)(src + e);
  const float4 v1 = *(const float4*)(src + e + 4);
  short8 p;
  p[0] = (short)cvt_bf(v0.x); p[1] = (short)cvt_bf(v0.y);
  p[2] = (short)cvt_bf(v0.z); p[3] = (short)cvt_bf(v0.w);
  p[4] = (short)cvt_bf(v1.x); p[5] = (short)cvt_bf(v1.y);
  p[6] = (short)cvt_bf(v1.z); p[7] = (short)cvt_bf(v1.w);
  *(short8*)(dst + e) = p;
}
__global__ __launch_bounds__(256)
void zerof(float* __restrict__ p) { p[blockIdx.x * 256 + threadIdx.x] = 0.f; }

// ---------------------------------------------------------------------------
// m97-style bf16 GEMM: out[M,N] = A[M,K](stride sa) @ B[N,K]^T(stride sb).
// 128x128 tile, BK=64, 256 thr / 4 waves, wave = 64x64 (4x4 MFMA tiles).
// Staging: global_load_lds 16B, rows 128 B, 8-slot XOR swizzle (<=2-way = free).
// MODE 0: out = acc + bias0[col] + bias1[col].   blockIdx.z swaps to group-2 ptrs.
// MODE 1: atomicAdd per-row of sum_col Walpha[col]*tanh(acc + atth[b*512+col]).
template<int MODE>
__global__ __launch_bounds__(256, 3)
void gemm128(const u16* __restrict__ A, int sa, const u16* __restrict__ B, int sb,
             const float* __restrict__ bias0, const float* __restrict__ bias1,
             float* __restrict__ out, int N, int K,
             const float* __restrict__ atth, const float* __restrict__ Walpha,
             float* __restrict__ scores, int row0,
             const u16* A2, const u16* B2,
             const float* bias0b, const float* bias1b, float* out2)
{
  if (blockIdx.z) { A = A2; B = B2; bias0 = bias0b; bias1 = bias1b; out = out2; }
  __shared__ u16 sA[128 * 64];   // 16 KB
  __shared__ u16 sB[128 * 64];   // 16 KB

  const int tid = threadIdx.x, lane = tid & 63, w = tid >> 6;
  const int quad = lane >> 4, l15 = lane & 15;
  const int wm = w >> 1, wn = w & 1;
  const int Mbase = blockIdx.y * 128, Nbase = blockIdx.x * 128;
  const int srow = lane >> 3;                // 0..7 within 8-row chunk
  const int sslot = (lane & 7) ^ srow;       // fetch-side xor swizzle

  floatx4 acc[4][4] = {};

  for (int k0 = 0; k0 < K; k0 += 64) {
    __syncthreads();   // prev tile consumed
#pragma unroll
    for (int j = 0; j < 4; ++j) {
      const int c = w + 4 * j;               // chunk 0..15 (8 rows x 128 B)
      const int row = c * 8 + srow;
      gll16(A + (size_t)(Mbase + row) * sa + k0 + sslot * 8, &sA[c * 512]);
      gll16(B + (size_t)(Nbase + row) * sb + k0 + sslot * 8, &sB[c * 512]);
    }
    __syncthreads();   // barrier drains vmcnt
#pragma unroll
    for (int ks = 0; ks < 2; ++ks) {
      short8 af[4], bf[4];
#pragma unroll
      for (int mt = 0; mt < 4; ++mt) {
        const int row = wm * 64 + mt * 16 + l15;
        af[mt] = *(const short8*)&sA[row * 64 + ((ks * 4 + quad) ^ (row & 7)) * 8];
      }
#pragma unroll
      for (int nt = 0; nt < 4; ++nt) {
        const int row = wn * 64 + nt * 16 + l15;
        bf[nt] = *(const short8*)&sB[row * 64 + ((ks * 4 + quad) ^ (row & 7)) * 8];
      }
#pragma unroll
      for (int mt = 0; mt < 4; ++mt)
#pragma unroll
        for (int nt = 0; nt < 4; ++nt)
          acc[mt][nt] = __builtin_amdgcn_mfma_f32_16x16x32_bf16(af[mt], bf[nt], acc[mt][nt], 0, 0, 0);
    }
  }

  if (MODE == 0) {
#pragma unroll
    for (int nt = 0; nt < 4; ++nt) {
      const int col = Nbase + wn * 64 + nt * 16 + l15;
      const float bc = bias0[col] + bias1[col];
#pragma unroll
      for (int mt = 0; mt < 4; ++mt) {
        const int rb = Mbase + wm * 64 + mt * 16 + quad * 4;
#pragma unroll
        for (int r = 0; r < 4; ++r)
          out[(size_t)(rb + r) * N + col] = acc[mt][nt][r] + bc;
      }
    }
  } else {
    const int b = (row0 + Mbase + wm * 64) >> 6;   // one batch per wave stripe
    float rs[4][4] = {};
#pragma unroll
    for (int nt = 0; nt < 4; ++nt) {
      const int col = Nbase + wn * 64 + nt * 16 + l15;
      const float wa = Walpha[col];
      const float ah = atth[(size_t)b * 512 + col];
#pragma unroll
      for (int mt = 0; mt < 4; ++mt)
#pragma unroll
        for (int r = 0; r < 4; ++r)
          rs[mt][r] += wa * fast_tanh(acc[mt][nt][r] + ah);
    }
#pragma unroll
    for (int mt = 0; mt < 4; ++mt)
#pragma unroll
      for (int r = 0; r < 4; ++r) {
        float v = rs[mt][r];
        v += __shfl_xor(v, 1); v += __shfl_xor(v, 2);
        v += __shfl_xor(v, 4); v += __shfl_xor(v, 8);
        if (l15 == 0)
          atomicAdd(&scores[row0 + Mbase + wm * 64 + mt * 16 + quad * 4 + r], v);
      }
  }
}

// ---------------------------------------------------------------------------
// masked softmax over S=64, one wave per batch (b_alpha constant cancels)
__global__ __launch_bounds__(256)
void softmax_k(const float* __restrict__ scores, const int* __restrict__ mask,
               float* __restrict__ wbuf)
{
  const int b = blockIdx.x * 4 + (threadIdx.x >> 6);
  const int s = threadIdx.x & 63;
  const float v = scores[b * 64 + s];
  float mx = v;
#pragma unroll
  for (int d = 32; d; d >>= 1) mx = fmaxf(mx, __shfl_xor(mx, d));
  const float e = __expf(v - mx) * (float)mask[b * 64 + s];
  float den = e;
#pragma unroll
  for (int d = 32; d; d >>= 1) den += __shfl_xor(den, d);
  wbuf[b * 64 + s] = e / den;
}

// ---------------------------------------------------------------------------
// att[b,:] = sum_s w[s]*clip[b,s,:] -> bf16 into A1 cols 1024..2047.
// BF=1 reads bf16 clipb (full), BF=0 reads fp32 clip.
template<int BF>
__global__ __launch_bounds__(128)
void ctx_att(const float* __restrict__ clipf, const u16* __restrict__ clipb,
             const float* __restrict__ wbuf, u16* __restrict__ A1)
{
  __shared__ float w[64];
  const int b = blockIdx.x, tid = threadIdx.x;
  if (tid < 64) w[tid] = wbuf[b * 64 + tid];
  __syncthreads();
  const int c8 = tid * 8;
  float a[8] = {};
  if (BF) {
    const u16* base = clipb + (size_t)b * 65536 + c8;
#pragma unroll 4
    for (int s = 0; s < 64; ++s) {
      const float wt = w[s];
      const short8 c = *(const short8*)(base + (size_t)s * 1024);
#pragma unroll
      for (int j = 0; j < 8; ++j) a[j] += wt * bf2f((u16)c[j]);
    }
  } else {
    const float* base = clipf + (size_t)b * 65536 + c8;
#pragma unroll 4
    for (int s = 0; s < 64; ++s) {
      const float wt = w[s];
      const float4 v0 = *(const float4*)(base + (size_t)s * 1024);
      const float4 v1 = *(const float4*)(base + (size_t)s * 1024 + 4);
      a[0] += wt * v0.x; a[1] += wt * v0.y; a[2] += wt * v0.z; a[3] += wt * v0.w;
      a[4] += wt * v1.x; a[5] += wt * v1.y; a[6] += wt * v1.z; a[7] += wt * v1.w;
    }
  }
  short8 p;
#pragma unroll
  for (int j = 0; j < 8; ++j) p[j] = (short)cvt_bf(a[j]);
  *(short8*)&A1[(size_t)b * 3072 + 1024 + c8] = p;
}

// ---------------------------------------------------------------------------
__global__ __launch_bounds__(256)
void lstm_ew(const float* __restrict__ gates, const float* __restrict__ cprev,
             float* __restrict__ out, int st)
{
  const int idx = blockIdx.x * 256 + threadIdx.x;
  const int b = idx >> 8;
  const int r4 = (idx & 255) * 4;
  const float* g = gates + (size_t)b * 4096 + r4;
  const float4 gi = *(const float4*)g;
  const float4 gf = *(const float4*)(g + 1024);
  const float4 gg = *(const float4*)(g + 2048);
  const float4 go = *(const float4*)(g + 3072);
  const float4 c  = *(const float4*)(cprev + (size_t)b * 1024 + r4);
  float4 cn, hn;
  cn.x = fast_sigm(gf.x) * c.x + fast_sigm(gi.x) * fast_tanh(gg.x);  hn.x = fast_sigm(go.x) * fast_tanh(cn.x);
  cn.y = fast_sigm(gf.y) * c.y + fast_sigm(gi.y) * fast_tanh(gg.y);  hn.y = fast_sigm(go.y) * fast_tanh(cn.y);
  cn.z = fast_sigm(gf.z) * c.z + fast_sigm(gi.z) * fast_tanh(gg.z);  hn.z = fast_sigm(go.z) * fast_tanh(cn.z);
  cn.w = fast_sigm(gf.w) * c.w + fast_sigm(gi.w) * fast_tanh(gg.w);  hn.w = fast_sigm(go.w) * fast_tanh(cn.w);
  *(float4*)(out + (size_t)b * 2048 + st * 1024 + r4) = hn;
  *(float4*)(out + 2097152 + (size_t)st * 1048576 + (size_t)b * 1024 + r4) = hn;
  *(float4*)(out + 4194304 + (size_t)st * 1048576 + (size_t)b * 1024 + r4) = cn;
}

// ---------------------------------------------------------------------------
extern "C" void kernel_launch(void* const* d_in, const int* in_sizes, int n_in,
                              void* d_out, int out_size, void* d_ws, size_t ws_size,
                              hipStream_t stream) {
  (void)in_sizes; (void)n_in; (void)out_size;
  const float* xt      = (const float*)d_in[0];
  const float* event   = (const float*)d_in[2];
  const float* clip    = (const float*)d_in[3];
  const int*   cmask   = (const int*)d_in[4];
  const float* state_h = (const float*)d_in[5];
  const float* state_c = (const float*)d_in[6];
  const float* W_ih0   = (const float*)d_in[7];
  const float* b_ih0   = (const float*)d_in[8];
  const float* W_hh0   = (const float*)d_in[9];
  const float* b_hh0   = (const float*)d_in[10];
  const float* W_ih1   = (const float*)d_in[11];
  const float* b_ih1   = (const float*)d_in[12];
  const float* W_hh1   = (const float*)d_in[13];
  const float* b_hh1   = (const float*)d_in[14];
  const float* W_ctx   = (const float*)d_in[15];
  const float* b_ctx   = (const float*)d_in[16];
  const float* W_h2a   = (const float*)d_in[17];
  const float* b_h2a   = (const float*)d_in[18];
  const float* W_alpha = (const float*)d_in[19];

  // ws_size tiering: clipb (bf16 clip) chunked if scratch is tight.
  // grouped prefix = 2*gates + 2*A + W0 + Wc + Wh = 73,400,320 B
  int NC; bool grouped;
  if      (ws_size >= 207618048) { NC = 1; grouped = true;  }
  else if (ws_size >= 106954752) { NC = 4; grouped = true;  }
  else                           { NC = 8; grouped = false; }  // 81,788,928 B

  char* p = (char*)d_ws;
  float* gates0 = (float*)p; p += 16777216;
  float* gates1 = gates0;
  if (grouped) { gates1 = (float*)p; p += 16777216; }
  u16* A0 = (u16*)p; p += 6291456;      // [1024][3072] = [xt|event|h0p]
  u16* A1 = (u16*)p; p += 6291456;      // [1024][3072] = [xt|att|h1p]
  u16* W0 = (u16*)p; p += 25165824;     // [4096][3072] = [W_ih0|W_hh0]
  u16* Wc = (u16*)p; p += 1048576;      // [512][1024]
  u16* Wh = (u16*)p; p += 1048576;      // [512][1024]
  u16* clipb = (u16*)p;                 // chunk of bf16 clip
  u16* W1 = (u16*)p;                    // aliases clipb; converted AFTER ctx_att
  // small fp32 buffers carved from gates0 (gates0 written only at the end)
  float* atth   = gates0;               // 1024*512
  float* wbuf   = gates0 + 524288;      // 1024*64
  float* scores = gates0 + 589824;      // 1024*64

  const float* h0p = state_h;
  const float* h1p = state_h + 1048576;
  const float* c0p = state_c;
  const float* c1p = state_c + 1048576;
  float* out = (float*)d_out;

  // 1. convert weights (except W1) + activations to bf16
  ConvArgs ca{};
  {
    const float* srcs[9] = {W_ctx, W_h2a, W_ih0, W_hh0, xt, event, h0p, xt, h1p};
    u16* dsts[9] = {Wc, Wh, W0, W0 + 2048, A0, A0 + 1024, A0 + 2048, A1, A1 + 2048};
    const unsigned lws[9]  = {10, 10, 11, 10, 10, 10, 10, 10, 10};
    const unsigned dstr[9] = {1024, 1024, 3072, 3072, 3072, 3072, 3072, 3072, 3072};
    const unsigned nblk[9] = {256, 256, 4096, 2048, 512, 512, 512, 512, 512};
    unsigned acc = 0;
    for (int i = 0; i < 9; ++i) {
      ca.src[i] = srcs[i]; ca.dst[i] = dsts[i];
      ca.lw[i] = lws[i]; ca.dstride[i] = dstr[i];
      ca.blk0[i] = acc; acc += nblk[i];
    }
    ca.blk0[9] = acc; ca.nseg = 9;
    convert_seg<<<acc, 256, 0, stream>>>(ca);   // 9216 blocks
  }

  // 2. scores = 0
  zerof<<<256, 256, 0, stream>>>(scores);

  // 3. atth = h1p @ W_h2a^T + b_h2a + b_ctx   [1024 x 512]
  gemm128<0><<<dim3(4, 8, 1), 256, 0, stream>>>(
      A1 + 2048, 3072, Wh, 1024, b_h2a, b_ctx, atth, 512, 1024,
      nullptr, nullptr, nullptr, 0, nullptr, nullptr, nullptr, nullptr, nullptr);

  // 4. clip conversion + score GEMM, chunked over M
  const int rows = 65536 / NC;
  for (int c = 0; c < NC; ++c) {
    conv_flat<<<rows * 1024 / 2048, 256, 0, stream>>>(clip + (size_t)c * rows * 1024, clipb);
    gemm128<1><<<dim3(4, rows / 128, 1), 256, 0, stream>>>(
        clipb, 1024, Wc, 1024, nullptr, nullptr, nullptr, 512, 1024,
        atth, W_alpha, scores, c * rows,
        nullptr, nullptr, nullptr, nullptr, nullptr);
  }

  // 5. masked softmax -> weights
  softmax_k<<<256, 256, 0, stream>>>(scores, cmask, wbuf);

  // 6. att = w @ clip -> bf16 into A1 middle cols
  if (NC == 1) ctx_att<1><<<1024, 128, 0, stream>>>(clip, clipb, wbuf, A1);
  else         ctx_att<0><<<1024, 128, 0, stream>>>(clip, clipb, wbuf, A1);

  // 7. convert W1 (into clipb-aliased region — clipb dead now)
  ConvArgs cb{};
  {
    const float* srcs[2] = {W_ih1, W_hh1};
    u16* dsts[2] = {W1, W1 + 2048};
    const unsigned lws[2] = {11, 10};
    const unsigned nblk[2] = {4096, 2048};
    unsigned acc = 0;
    for (int i = 0; i < 2; ++i) {
      cb.src[i] = srcs[i]; cb.dst[i] = dsts[i];
      cb.lw[i] = lws[i]; cb.dstride[i] = 3072;
      cb.blk0[i] = acc; acc += nblk[i];
    }
    cb.blk0[2] = acc; cb.nseg = 2;
    convert_seg<<<acc, 256, 0, stream>>>(cb);   // 6144 blocks
  }

  // 8. gates GEMMs (+ biases) and LSTM elementwise
  if (grouped) {
    gemm128<0><<<dim3(32, 8, 2), 256, 0, stream>>>(
        A0, 3072, W0, 3072, b_ih0, b_hh0, gates0, 4096, 3072,
        nullptr, nullptr, nullptr, 0,
        A1, W1, b_ih1, b_hh1, gates1);
    lstm_ew<<<1024, 256, 0, stream>>>(gates0, c0p, out, 0);
    lstm_ew<<<1024, 256, 0, stream>>>(gates1, c1p, out, 1);
  } else {
    gemm128<0><<<dim3(32, 8, 1), 256, 0, stream>>>(
        A0, 3072, W0, 3072, b_ih0, b_hh0, gates0, 4096, 3072,
        nullptr, nullptr, nullptr, 0, nullptr, nullptr, nullptr, nullptr, nullptr);
    lstm_ew<<<1024, 256, 0, stream>>>(gates0, c0p, out, 0);
    gemm128<0><<<dim3(32, 8, 1), 256, 0, stream>>>(
        A1, 3072, W1, 3072, b_ih1, b_hh1, gates0, 4096, 3072,
        nullptr, nullptr, nullptr, 0, nullptr, nullptr, nullptr, nullptr, nullptr);
    lstm_ew<<<1024, 256, 0, stream>>>(gates0, c1p, out, 1);
  }
}